// Round 4
// baseline (2466.433 us; speedup 1.0000x reference)
//
#include <hip/hip_runtime.h>
#include <math.h>

#define BB 512
#define SS 2048
#define DD 19
#define HH 40
#define CH 32
#define NCH (SS / CH)   // 64 chunks
#define XS 33           // xg col stride ([row][XS]); 33 -> bank (row+t), conflict-free
#define RS 33           // ring col stride ([unit][RS])

__device__ __forceinline__ float sigm_fast(float x) {
    float e = __expf(x);
    float r = __builtin_amdgcn_rcpf(e + 1.0f);
    return fmaf(-1.0f, r, 1.0f);
}
__device__ __forceinline__ float tanh_fast(float x) {
    float e = __expf(2.0f * x);
    float r = __builtin_amdgcn_rcpf(e + 1.0f);
    return fmaf(-2.0f, r, 1.0f);
}
__device__ __forceinline__ float bcast_lane(float v, int k) {
    return __uint_as_float(__builtin_amdgcn_readlane(__float_as_uint(v), k));
}

__global__ __launch_bounds__(128, 1)  // cap 512 VGPR: weights must NOT spill
void lstm_fused(const float* __restrict__ x,
                const float* __restrict__ W_ih,
                const float* __restrict__ W_hh,
                const float* __restrict__ b_ih,
                const float* __restrict__ b_hh,
                const float* __restrict__ ln_g,
                const float* __restrict__ ln_b,
                const float* __restrict__ W1,
                const float* __restrict__ b1,
                const float* __restrict__ W2,
                const float* __restrict__ b2,
                const float* __restrict__ Wo,
                const float* __restrict__ bo,
                const float* __restrict__ log_thr,
                float* __restrict__ out) {
    __shared__ float s_xg[2][4 * HH][XS];    // 42.2 KB, [row][t] transposed
    __shared__ float s_ring[2][HH][RS];      // 10.6 KB, [unit][t] transposed
    __shared__ __align__(16) float s_x[CH][20];  // 2.6 KB
    __shared__ __align__(16) float s_W1[HH * HH];
    __shared__ __align__(16) float s_W2[HH * HH];
    __shared__ float s_b1[HH], s_b2[HH], s_lng[HH], s_lnb[HH], s_Wo[HH];

    const int tid = threadIdx.x;
    const int lane = tid & 63;
    const int wave = tid >> 6;
    const int b = blockIdx.x;

    // ---- cooperative staging ----
    for (int i = tid; i < HH * HH; i += 128) { s_W1[i] = W1[i]; s_W2[i] = W2[i]; }
    if (tid < HH) {
        s_b1[tid] = b1[tid]; s_b2[tid] = b2[tid];
        s_lng[tid] = ln_g[tid]; s_lnb[tid] = ln_b[tid]; s_Wo[tid] = Wo[tid];
    }

    const float bo0 = bo[0];
    const float thrv = expf(log_thr[0]);

    // ---- producer persistent state (wave 0): lane u owns unit u, 4 gate rows ----
    float wI[HH], wF[HH], wG[HH], wO[HH];
    float cc = 0.0f, hh = 0.0f;
    const int uu = (lane < HH) ? lane : (HH - 1);  // lanes 40-63 mirror lane 39 (harmless)
    if (wave == 0) {
        const float4* rI = (const float4*)&W_hh[(0 * HH + uu) * HH];
        const float4* rF = (const float4*)&W_hh[(1 * HH + uu) * HH];
        const float4* rG = (const float4*)&W_hh[(2 * HH + uu) * HH];
        const float4* rO = (const float4*)&W_hh[(3 * HH + uu) * HH];
#pragma unroll
        for (int q = 0; q < 10; ++q) {
            float4 f;
            f = rI[q]; wI[4*q]=f.x; wI[4*q+1]=f.y; wI[4*q+2]=f.z; wI[4*q+3]=f.w;
            f = rF[q]; wF[4*q]=f.x; wF[4*q+1]=f.y; wF[4*q+2]=f.z; wF[4*q+3]=f.w;
            f = rG[q]; wG[4*q]=f.x; wG[4*q+1]=f.y; wG[4*q+2]=f.z; wG[4*q+3]=f.w;
            f = rO[q]; wO[4*q]=f.x; wO[4*q+1]=f.y; wO[4*q+2]=f.z; wO[4*q+3]=f.w;
        }
    }

    // ---- helper persistent state (wave 1): W_ih rows in regs (2.5 rows/lane) ----
    float wx0[DD], wx1[DD], wx2[DD];
    float bs0 = 0.f, bs1 = 0.f, bs2 = 0.f;
    if (wave == 1) {
        const int r0 = lane, r1 = 64 + lane, r2 = 128 + (lane & 31);
#pragma unroll
        for (int d = 0; d < DD; ++d) {
            wx0[d] = W_ih[r0 * DD + d];
            wx1[d] = W_ih[r1 * DD + d];
            wx2[d] = W_ih[r2 * DD + d];
        }
        bs0 = b_ih[r0] + b_hh[r0];
        bs1 = b_ih[r1] + b_hh[r1];
        bs2 = b_ih[r2] + b_hh[r2];
    }

    // ================= role bodies =================
    auto produce = [&](int ch) {
        float (*xg)[XS] = s_xg[ch & 1];
        float (*rg)[RS] = s_ring[ch & 1];
        float pi = xg[uu][0], pf = xg[HH + uu][0];
        float pg = xg[2 * HH + uu][0], po = xg[3 * HH + uu][0];
#pragma unroll 1
        for (int t = 0; t < CH; ++t) {
            // broadcast h (prev step) into wave-uniform values (SGPRs)
            float hb[HH];
#pragma unroll
            for (int k = 0; k < HH; ++k) hb[k] = bcast_lane(hh, k);
            float ai = pi, af = pf, ag = pg, ao = po;
            if (t + 1 < CH) {  // prefetch next step's xg
                pi = xg[uu][t + 1]; pf = xg[HH + uu][t + 1];
                pg = xg[2 * HH + uu][t + 1]; po = xg[3 * HH + uu][t + 1];
            }
#pragma unroll
            for (int k = 0; k < HH; ++k) {
                ai = fmaf(hb[k], wI[k], ai);
                af = fmaf(hb[k], wF[k], af);
                ag = fmaf(hb[k], wG[k], ag);
                ao = fmaf(hb[k], wO[k], ao);
            }
            float gi = sigm_fast(ai), gf = sigm_fast(af);
            float gg = tanh_fast(ag), go = sigm_fast(ao);
            cc = fmaf(gf, cc, gi * gg);
            hh = go * tanh_fast(cc);
            if (lane < HH) rg[lane][t] = hh;  // banks (lane+t): conflict-free
        }
    };

    auto do_xg = [&](int ch) {
        float (*xg)[XS] = s_xg[ch & 1];
        // stage x chunk (coalesced)
        const float* xp = x + ((size_t)b * SS + (size_t)ch * CH) * DD;
        for (int i = lane; i < CH * DD; i += 64) s_x[i / DD][i % DD] = xp[i];
        asm volatile("s_waitcnt vmcnt(0) lgkmcnt(0)" ::: "memory");
#pragma unroll 1
        for (int t = 0; t < CH; ++t) {
            const float4* xr = (const float4*)&s_x[t][0];  // uniform -> broadcast reads
            float xv[20];
#pragma unroll
            for (int q = 0; q < 5; ++q) {
                float4 f = xr[q];
                xv[4*q]=f.x; xv[4*q+1]=f.y; xv[4*q+2]=f.z; xv[4*q+3]=f.w;
            }
            float a0 = bs0, a1 = bs1, a2 = bs2;
            float c0 = 0.f, c1 = 0.f, c2 = 0.f;
#pragma unroll
            for (int d = 0; d < DD; d += 2) {
                a0 = fmaf(wx0[d], xv[d], a0);
                a1 = fmaf(wx1[d], xv[d], a1);
                a2 = fmaf(wx2[d], xv[d], a2);
                if (d + 1 < DD) {
                    c0 = fmaf(wx0[d+1], xv[d+1], c0);
                    c1 = fmaf(wx1[d+1], xv[d+1], c1);
                    c2 = fmaf(wx2[d+1], xv[d+1], c2);
                }
            }
            xg[lane][t] = a0 + c0;
            xg[64 + lane][t] = a1 + c1;
            if (lane < 32) xg[128 + (lane & 31)][t] = a2 + c2;
        }
    };

    auto consume = [&](int ch) {
        const int s = (lane < CH) ? lane : (CH - 1);  // lane = step
        float (*rg)[RS] = s_ring[ch & 1];
        float hv[HH];
#pragma unroll
        for (int k = 0; k < HH; ++k) hv[k] = rg[k][s];  // banks (k+s): conflict-free
        // LayerNorm
        float m0 = 0.f, m1 = 0.f, q0 = 0.f, q1 = 0.f;
#pragma unroll
        for (int k = 0; k < HH; k += 2) {
            m0 += hv[k]; m1 += hv[k + 1];
            q0 = fmaf(hv[k], hv[k], q0); q1 = fmaf(hv[k + 1], hv[k + 1], q1);
        }
        float mu = (m0 + m1) * (1.0f / HH);
        float var = (q0 + q1) * (1.0f / HH) - mu * mu;
        float inv = 1.0f / sqrtf(var + 1e-5f);
#pragma unroll
        for (int k = 0; k < HH; ++k)
            hv[k] = fmaf((hv[k] - mu) * inv, s_lng[k], s_lnb[k]);  // hv := ln
        // head part 1: sigmoid(ln).Wo
        float part = 0.f;
#pragma unroll
        for (int k = 0; k < HH; ++k) part = fmaf(sigm_fast(hv[k]), s_Wo[k], part);
        // MLP1
        float r1v[HH];
#pragma unroll 2
        for (int j = 0; j < HH; ++j) {
            const float4* wr = (const float4*)&s_W1[j * HH];
            float a0 = s_b1[j], a1 = 0.f;
#pragma unroll
            for (int q = 0; q < 10; ++q) {
                float4 w4 = wr[q];
                a0 = fmaf(w4.x, hv[4*q], a0);   a1 = fmaf(w4.y, hv[4*q+1], a1);
                a0 = fmaf(w4.z, hv[4*q+2], a0); a1 = fmaf(w4.w, hv[4*q+3], a1);
            }
            r1v[j] = tanh_fast(a0 + a1);
        }
        // MLP2 + head part 2
#pragma unroll 2
        for (int j = 0; j < HH; ++j) {
            const float4* wr = (const float4*)&s_W2[j * HH];
            float a0 = s_b2[j], a1 = 0.f;
#pragma unroll
            for (int q = 0; q < 10; ++q) {
                float4 w4 = wr[q];
                a0 = fmaf(w4.x, r1v[4*q], a0);   a1 = fmaf(w4.y, r1v[4*q+1], a1);
                a0 = fmaf(w4.z, r1v[4*q+2], a0); a1 = fmaf(w4.w, r1v[4*q+3], a1);
            }
            float r2 = tanh_fast(a0 + a1);
            part = fmaf(r2, s_Wo[j], part);
        }
        float raw = tanh_fast(part + bo0);
        if (lane < CH) {
            float sg = (fabsf(raw) >= thrv) ? raw : 0.0f;
            out[(size_t)b * SS + (size_t)ch * CH + lane] = sg;
        }
    };

    // ================= schedule =================
    __syncthreads();              // weights staged
    if (wave == 1) do_xg(0);
    __syncthreads();

    for (int ph = 0; ph <= NCH; ++ph) {
        if (wave == 0) {
            if (ph < NCH) produce(ph);
        } else {
            if (ph + 1 < NCH) do_xg(ph + 1);
            if (ph >= 1) consume(ph - 1);
        }
        __syncthreads();
    }

    // ---- final states + threshold scalar ----
    if (wave == 0 && lane < HH) {
        out[(size_t)BB * SS + (size_t)b * HH + lane] = hh;
        out[(size_t)BB * SS + (size_t)BB * HH + (size_t)b * HH + lane] = cc;
    }
    if (b == 0 && tid == 0) {
        out[(size_t)BB * SS + 2 * (size_t)BB * HH] = thrv;
    }
}

extern "C" void kernel_launch(void* const* d_in, const int* in_sizes, int n_in,
                              void* d_out, int out_size, void* d_ws, size_t ws_size,
                              hipStream_t stream) {
    const float* x    = (const float*)d_in[0];
    const float* W_ih = (const float*)d_in[1];
    const float* W_hh = (const float*)d_in[2];
    const float* b_ih = (const float*)d_in[3];
    const float* b_hh = (const float*)d_in[4];
    const float* ln_g = (const float*)d_in[5];
    const float* ln_b = (const float*)d_in[6];
    const float* W1   = (const float*)d_in[7];
    const float* b1   = (const float*)d_in[8];
    const float* W2   = (const float*)d_in[9];
    const float* b2   = (const float*)d_in[10];
    const float* Wo   = (const float*)d_in[11];
    const float* bo   = (const float*)d_in[12];
    const float* lt   = (const float*)d_in[13];
    float* out = (float*)d_out;

    lstm_fused<<<dim3(BB), dim3(128), 0, stream>>>(
        x, W_ih, W_hh, b_ih, b_hh, ln_g, ln_b, W1, b1, W2, b2, Wo, bo, lt, out);
}

// Round 5
// 2425.761 us; speedup vs baseline: 1.0168x; 1.0168x over previous
//
#include <hip/hip_runtime.h>
#include <math.h>

#define BB 512
#define SS 2048
#define DD 19
#define HH 40
#define CH 32
#define NCH (SS / CH)   // 64 chunks
#define XS 33           // xg col stride ([row][XS]); banks (row+t), conflict-free
#define RS 33           // ring col stride ([unit][RS])

__device__ __forceinline__ float sigm_fast(float x) {
    float e = __expf(x);
    float r = __builtin_amdgcn_rcpf(e + 1.0f);
    return fmaf(-1.0f, r, 1.0f);
}
__device__ __forceinline__ float tanh_fast(float x) {
    float e = __expf(2.0f * x);
    float r = __builtin_amdgcn_rcpf(e + 1.0f);
    return fmaf(-2.0f, r, 1.0f);
}

__global__ __launch_bounds__(128, 1)  // 1 wave/EU min -> VGPR cap 512: weights never spill
void lstm_fused(const float* __restrict__ x,
                const float* __restrict__ W_ih,
                const float* __restrict__ W_hh,
                const float* __restrict__ b_ih,
                const float* __restrict__ b_hh,
                const float* __restrict__ ln_g,
                const float* __restrict__ ln_b,
                const float* __restrict__ W1,
                const float* __restrict__ b1,
                const float* __restrict__ W2,
                const float* __restrict__ b2,
                const float* __restrict__ Wo,
                const float* __restrict__ bo,
                const float* __restrict__ log_thr,
                float* __restrict__ out) {
    __shared__ float s_xg[2][4 * HH][XS];        // 42.2 KB, [row][t]
    __shared__ float s_ring[2][HH][RS];          // 10.6 KB, [unit][t]
    __shared__ __align__(16) float s_hrow[64];   // current h (wave-private use)
    __shared__ __align__(16) float s_x[CH][20];  // 2.6 KB
    __shared__ __align__(16) float s_W1[HH * HH];
    __shared__ __align__(16) float s_W2[HH * HH];
    __shared__ float s_b1[HH], s_b2[HH], s_lng[HH], s_lnb[HH], s_Wo[HH];

    const int tid = threadIdx.x;
    const int lane = tid & 63;
    const int wave = tid >> 6;
    const int b = blockIdx.x;

    // ---- cooperative staging ----
    for (int i = tid; i < HH * HH; i += 128) { s_W1[i] = W1[i]; s_W2[i] = W2[i]; }
    if (tid < HH) {
        s_b1[tid] = b1[tid]; s_b2[tid] = b2[tid];
        s_lng[tid] = ln_g[tid]; s_lnb[tid] = ln_b[tid]; s_Wo[tid] = Wo[tid];
    }

    const float bo0 = bo[0];
    const float thrv = expf(log_thr[0]);

    // ---- producer persistent state (wave 0): lane u owns unit u, 4 gate rows ----
    float wI[HH], wF[HH], wG[HH], wO[HH];
    float cc = 0.0f, hh = 0.0f;
    const int uu = (lane < HH) ? lane : (HH - 1);  // lanes 40-63 mirror unit 39 (harmless)
    if (wave == 0) {
        const float4* rI = (const float4*)&W_hh[(0 * HH + uu) * HH];
        const float4* rF = (const float4*)&W_hh[(1 * HH + uu) * HH];
        const float4* rG = (const float4*)&W_hh[(2 * HH + uu) * HH];
        const float4* rO = (const float4*)&W_hh[(3 * HH + uu) * HH];
#pragma unroll
        for (int q = 0; q < 10; ++q) {
            float4 f;
            f = rI[q]; wI[4*q]=f.x; wI[4*q+1]=f.y; wI[4*q+2]=f.z; wI[4*q+3]=f.w;
            f = rF[q]; wF[4*q]=f.x; wF[4*q+1]=f.y; wF[4*q+2]=f.z; wF[4*q+3]=f.w;
            f = rG[q]; wG[4*q]=f.x; wG[4*q+1]=f.y; wG[4*q+2]=f.z; wG[4*q+3]=f.w;
            f = rO[q]; wO[4*q]=f.x; wO[4*q+1]=f.y; wO[4*q+2]=f.z; wO[4*q+3]=f.w;
        }
        s_hrow[lane] = 0.0f;   // h0 = 0 (same-wave in-order vs first read)
    }

    // ---- helper persistent state (wave 1): W_ih rows in regs (2.5 rows/lane) ----
    float wx0[DD], wx1[DD], wx2[DD];
    float bs0 = 0.f, bs1 = 0.f, bs2 = 0.f;
    if (wave == 1) {
        const int r0 = lane, r1 = 64 + lane, r2 = 128 + (lane & 31);
#pragma unroll
        for (int d = 0; d < DD; ++d) {
            wx0[d] = W_ih[r0 * DD + d];
            wx1[d] = W_ih[r1 * DD + d];
            wx2[d] = W_ih[r2 * DD + d];
        }
        bs0 = b_ih[r0] + b_hh[r0];
        bs1 = b_ih[r1] + b_hh[r1];
        bs2 = b_ih[r2] + b_hh[r2];
    }

    // ================= role bodies =================
    auto produce = [&](int ch) {
        float (*xg)[XS] = s_xg[ch & 1];
        float (*rg)[RS] = s_ring[ch & 1];
        float pi = xg[uu][0], pf = xg[HH + uu][0];
        float pg = xg[2 * HH + uu][0], po = xg[3 * HH + uu][0];
#pragma unroll 1
        for (int t = 0; t < CH; ++t) {
            float ai = pi, af = pf, ag = pg, ao = po;
            // h broadcast: 10 uniform b128 reads of s_hrow (same-wave RAW, in-order DS pipe)
            const float4* h4 = (const float4*)s_hrow;
#pragma unroll
            for (int q = 0; q < 10; ++q) {
                float4 f = h4[q];
                ai = fmaf(f.x, wI[4*q+0], ai); af = fmaf(f.x, wF[4*q+0], af);
                ag = fmaf(f.x, wG[4*q+0], ag); ao = fmaf(f.x, wO[4*q+0], ao);
                ai = fmaf(f.y, wI[4*q+1], ai); af = fmaf(f.y, wF[4*q+1], af);
                ag = fmaf(f.y, wG[4*q+1], ag); ao = fmaf(f.y, wO[4*q+1], ao);
                ai = fmaf(f.z, wI[4*q+2], ai); af = fmaf(f.z, wF[4*q+2], af);
                ag = fmaf(f.z, wG[4*q+2], ag); ao = fmaf(f.z, wO[4*q+2], ao);
                ai = fmaf(f.w, wI[4*q+3], ai); af = fmaf(f.w, wF[4*q+3], af);
                ag = fmaf(f.w, wG[4*q+3], ag); ao = fmaf(f.w, wO[4*q+3], ao);
            }
            if (t + 1 < CH) {  // prefetch next step's xg
                pi = xg[uu][t + 1]; pf = xg[HH + uu][t + 1];
                pg = xg[2 * HH + uu][t + 1]; po = xg[3 * HH + uu][t + 1];
            }
            float gi = sigm_fast(ai), gf = sigm_fast(af);
            float gg = tanh_fast(ag), go = sigm_fast(ao);
            cc = fmaf(gf, cc, gi * gg);
            hh = go * tanh_fast(cc);
            s_hrow[lane] = hh;               // lanes 40-63 write pad (never read)
            if (lane < HH) rg[lane][t] = hh; // history for consumer
        }
    };

    auto do_xg = [&](int ch) {
        float (*xg)[XS] = s_xg[ch & 1];
        const float* xp = x + ((size_t)b * SS + (size_t)ch * CH) * DD;
        for (int i = lane; i < CH * DD; i += 64) s_x[i / DD][i % DD] = xp[i];
        asm volatile("s_waitcnt vmcnt(0) lgkmcnt(0)" ::: "memory");
#pragma unroll 1
        for (int t = 0; t < CH; ++t) {
            const float4* xr = (const float4*)&s_x[t][0];
            float xv[20];
#pragma unroll
            for (int q = 0; q < 5; ++q) {
                float4 f = xr[q];
                xv[4*q]=f.x; xv[4*q+1]=f.y; xv[4*q+2]=f.z; xv[4*q+3]=f.w;
            }
            float a0 = bs0, a1 = bs1, a2 = bs2;
            float c0 = 0.f, c1 = 0.f, c2 = 0.f;
#pragma unroll
            for (int d = 0; d < DD; d += 2) {
                a0 = fmaf(wx0[d], xv[d], a0);
                a1 = fmaf(wx1[d], xv[d], a1);
                a2 = fmaf(wx2[d], xv[d], a2);
                if (d + 1 < DD) {
                    c0 = fmaf(wx0[d+1], xv[d+1], c0);
                    c1 = fmaf(wx1[d+1], xv[d+1], c1);
                    c2 = fmaf(wx2[d+1], xv[d+1], c2);
                }
            }
            xg[lane][t] = a0 + c0;
            xg[64 + lane][t] = a1 + c1;
            if (lane < 32) xg[128 + (lane & 31)][t] = a2 + c2;
        }
    };

    auto consume = [&](int ch) {
        const int s = (lane < CH) ? lane : (CH - 1);  // lane = step
        float (*rg)[RS] = s_ring[ch & 1];
        float hv[HH];
#pragma unroll
        for (int k = 0; k < HH; ++k) hv[k] = rg[k][s];  // banks (k+s): conflict-free
        float m0 = 0.f, m1 = 0.f, q0 = 0.f, q1 = 0.f;
#pragma unroll
        for (int k = 0; k < HH; k += 2) {
            m0 += hv[k]; m1 += hv[k + 1];
            q0 = fmaf(hv[k], hv[k], q0); q1 = fmaf(hv[k + 1], hv[k + 1], q1);
        }
        float mu = (m0 + m1) * (1.0f / HH);
        float var = (q0 + q1) * (1.0f / HH) - mu * mu;
        float inv = 1.0f / sqrtf(var + 1e-5f);
#pragma unroll
        for (int k = 0; k < HH; ++k)
            hv[k] = fmaf((hv[k] - mu) * inv, s_lng[k], s_lnb[k]);  // hv := ln
        float part = 0.f;
#pragma unroll
        for (int k = 0; k < HH; ++k) part = fmaf(sigm_fast(hv[k]), s_Wo[k], part);
        float r1v[HH];
#pragma unroll 2
        for (int j = 0; j < HH; ++j) {
            const float4* wr = (const float4*)&s_W1[j * HH];
            float a0 = s_b1[j], a1 = 0.f;
#pragma unroll
            for (int q = 0; q < 10; ++q) {
                float4 w4 = wr[q];
                a0 = fmaf(w4.x, hv[4*q], a0);   a1 = fmaf(w4.y, hv[4*q+1], a1);
                a0 = fmaf(w4.z, hv[4*q+2], a0); a1 = fmaf(w4.w, hv[4*q+3], a1);
            }
            r1v[j] = tanh_fast(a0 + a1);
        }
#pragma unroll 2
        for (int j = 0; j < HH; ++j) {
            const float4* wr = (const float4*)&s_W2[j * HH];
            float a0 = s_b2[j], a1 = 0.f;
#pragma unroll
            for (int q = 0; q < 10; ++q) {
                float4 w4 = wr[q];
                a0 = fmaf(w4.x, r1v[4*q], a0);   a1 = fmaf(w4.y, r1v[4*q+1], a1);
                a0 = fmaf(w4.z, r1v[4*q+2], a0); a1 = fmaf(w4.w, r1v[4*q+3], a1);
            }
            float r2 = tanh_fast(a0 + a1);
            part = fmaf(r2, s_Wo[j], part);
        }
        float raw = tanh_fast(part + bo0);
        if (lane < CH) {
            float sg = (fabsf(raw) >= thrv) ? raw : 0.0f;
            out[(size_t)b * SS + (size_t)ch * CH + lane] = sg;
        }
    };

    // ================= schedule =================
    __syncthreads();              // weights staged
    if (wave == 1) do_xg(0);
    __syncthreads();

    for (int ph = 0; ph <= NCH; ++ph) {
        if (wave == 0) {
            if (ph < NCH) produce(ph);
        } else {
            if (ph + 1 < NCH) do_xg(ph + 1);
            if (ph >= 1) consume(ph - 1);
        }
        __syncthreads();
    }

    // ---- final states + threshold scalar ----
    if (wave == 0 && lane < HH) {
        out[(size_t)BB * SS + (size_t)b * HH + lane] = hh;
        out[(size_t)BB * SS + (size_t)BB * HH + (size_t)b * HH + lane] = cc;
    }
    if (b == 0 && tid == 0) {
        out[(size_t)BB * SS + 2 * (size_t)BB * HH] = thrv;
    }
}

extern "C" void kernel_launch(void* const* d_in, const int* in_sizes, int n_in,
                              void* d_out, int out_size, void* d_ws, size_t ws_size,
                              hipStream_t stream) {
    const float* x    = (const float*)d_in[0];
    const float* W_ih = (const float*)d_in[1];
    const float* W_hh = (const float*)d_in[2];
    const float* b_ih = (const float*)d_in[3];
    const float* b_hh = (const float*)d_in[4];
    const float* ln_g = (const float*)d_in[5];
    const float* ln_b = (const float*)d_in[6];
    const float* W1   = (const float*)d_in[7];
    const float* b1   = (const float*)d_in[8];
    const float* W2   = (const float*)d_in[9];
    const float* b2   = (const float*)d_in[10];
    const float* Wo   = (const float*)d_in[11];
    const float* bo   = (const float*)d_in[12];
    const float* lt   = (const float*)d_in[13];
    float* out = (float*)d_out;

    lstm_fused<<<dim3(BB), dim3(128), 0, stream>>>(
        x, W_ih, W_hh, b_ih, b_hh, ln_g, ln_b, W1, b1, W2, b2, Wo, bo, lt, out);
}

// Round 6
// 1230.849 us; speedup vs baseline: 2.0038x; 1.9708x over previous
//
#include <hip/hip_runtime.h>
#include <math.h>

#define BB 512
#define SS 2048
#define DD 19
#define HH 40
#define CH 32
#define NCH (SS / CH)   // 64 chunks
#define RS 41           // ring row stride ([t][RS]); banks 9t+k, conflict-free
#define HS 48           // h buffer stride (16B aligned)

__device__ __forceinline__ float gate_act(float a, float mulk) {
    // mulk=1: sigmoid(a); mulk=2: tanh(a). 1 - mulk/(exp(mulk*a)+1), NaN-free.
    float e = __expf(a * mulk);
    float r = __builtin_amdgcn_rcpf(e + 1.0f);
    return fmaf(-mulk, r, 1.0f);
}
__device__ __forceinline__ float tanh_fast(float x) {
    float e = __expf(2.0f * x);
    float r = __builtin_amdgcn_rcpf(e + 1.0f);
    return fmaf(-2.0f, r, 1.0f);
}
__device__ __forceinline__ float sigm_fast(float x) {
    float e = __expf(x);
    float r = __builtin_amdgcn_rcpf(e + 1.0f);
    return fmaf(-1.0f, r, 1.0f);
}

__global__ __launch_bounds__(256, 2)  // VGPR cap 256 (no spill), 2 blocks/CU
void lstm_fused(const float* __restrict__ x,
                const float* __restrict__ W_ih,
                const float* __restrict__ W_hh,
                const float* __restrict__ b_ih,
                const float* __restrict__ b_hh,
                const float* __restrict__ ln_g,
                const float* __restrict__ ln_b,
                const float* __restrict__ W1,
                const float* __restrict__ b1,
                const float* __restrict__ W2,
                const float* __restrict__ b2,
                const float* __restrict__ Wo,
                const float* __restrict__ bo,
                const float* __restrict__ log_thr,
                float* __restrict__ out) {
    __shared__ float s_ring[CH][RS];             // h history; reused for r1
    __shared__ __align__(16) float s_h[2][HS];   // double-buffered current h
    __shared__ __align__(16) float s_x[CH][20];  // staged x chunk (19 + 1 pad)
    __shared__ __align__(16) float s_W1[HH * HH];
    __shared__ __align__(16) float s_W2[HH * HH];
    __shared__ float s_lng[HH], s_lnb[HH], s_Wo[HH], s_b1[HH], s_b2[HH];
    __shared__ float s_part[256];

    const int tid = threadIdx.x;
    const int b = blockIdx.x;

    // ---- cooperative staging of post-LSTM weights ----
    for (int i = tid; i < HH * HH; i += 256) { s_W1[i] = W1[i]; s_W2[i] = W2[i]; }
    if (tid < HH) {
        s_lng[tid] = ln_g[tid]; s_lnb[tid] = ln_b[tid]; s_Wo[tid] = Wo[tid];
        s_b1[tid] = b1[tid]; s_b2[tid] = b2[tid];
    }
    if (tid < HS) { s_h[0][tid] = 0.0f; s_h[1][tid] = 0.0f; }

    const float bo0 = bo[0];
    const float thrv = expf(log_thr[0]);

    // ---- gate thread setup: thread 4u+g owns gate row g*40+u ----
    const bool isGate = tid < 4 * HH;   // 160 gate threads (2.5 waves)
    const int g = tid & 3;
    const int u = tid >> 2;             // unit, <40 for gate threads
    const int grow = g * HH + u;
    const float mulk = (g == 2) ? 2.0f : 1.0f;

    float wih[DD];
    float whh[HH];
    float bsum = 0.0f;
    if (isGate) {
#pragma unroll
        for (int d = 0; d < DD; ++d) wih[d] = W_ih[grow * DD + d];
        const float4* wr = (const float4*)&W_hh[grow * HH];
#pragma unroll
        for (int q = 0; q < 10; ++q) {
            float4 f = wr[q];
            whh[4*q] = f.x; whh[4*q+1] = f.y; whh[4*q+2] = f.z; whh[4*q+3] = f.w;
        }
        bsum = b_ih[grow] + b_hh[grow];
    }
    float cc = 0.0f, hh = 0.0f;   // live in g==0 lanes

    // ---- x prefetch registers (3 elements/thread, chunk staged via regs) ----
    const int i0 = tid, i1 = tid + 256, i2 = tid + 512;     // of CH*DD = 608
    const int st0 = i0 / DD, d0 = i0 % DD;
    const int st1 = i1 / DD, d1 = i1 % DD;
    const int st2 = i2 / DD, d2 = i2 % DD;
    float xr0 = 0.f, xr1 = 0.f, xr2 = 0.f;
    {
        const float* xp = x + (size_t)b * SS * DD;   // chunk 0
        xr0 = xp[i0];
        xr1 = xp[i1];
        if (i2 < CH * DD) xr2 = xp[i2];
    }

    __syncthreads();   // weights + h init visible

    for (int ch = 0; ch < NCH; ++ch) {
        // ---- stage x chunk from prefetch regs; issue next chunk's loads ----
        s_x[st0][d0] = xr0;
        s_x[st1][d1] = xr1;
        if (i2 < CH * DD) s_x[st2][d2] = xr2;
        if (ch + 1 < NCH) {
            const float* xp = x + ((size_t)b * SS + (size_t)(ch + 1) * CH) * DD;
            xr0 = xp[i0];
            xr1 = xp[i1];
            if (i2 < CH * DD) xr2 = xp[i2];
        }
        __syncthreads();

        // ---- 32 recurrent steps, ONE barrier each ----
        for (int t = 0; t < CH; ++t) {
            if (isGate) {
                const float4* h4 = (const float4*)s_h[t & 1];
                const float4* x4 = (const float4*)&s_x[t][0];
                float a0 = bsum, a1 = 0.f, a2 = 0.f, a3 = 0.f;
                // x part: 19 FMAs (float4 bcast reads; [19] slot is pad, unused)
                float4 xa = x4[0], xb = x4[1], xc = x4[2], xd = x4[3], xe = x4[4];
                a0 = fmaf(xa.x, wih[0], a0);  a1 = fmaf(xa.y, wih[1], a1);
                a2 = fmaf(xa.z, wih[2], a2);  a3 = fmaf(xa.w, wih[3], a3);
                a0 = fmaf(xb.x, wih[4], a0);  a1 = fmaf(xb.y, wih[5], a1);
                a2 = fmaf(xb.z, wih[6], a2);  a3 = fmaf(xb.w, wih[7], a3);
                a0 = fmaf(xc.x, wih[8], a0);  a1 = fmaf(xc.y, wih[9], a1);
                a2 = fmaf(xc.z, wih[10], a2); a3 = fmaf(xc.w, wih[11], a3);
                a0 = fmaf(xd.x, wih[12], a0); a1 = fmaf(xd.y, wih[13], a1);
                a2 = fmaf(xd.z, wih[14], a2); a3 = fmaf(xd.w, wih[15], a3);
                a0 = fmaf(xe.x, wih[16], a0); a1 = fmaf(xe.y, wih[17], a1);
                a2 = fmaf(xe.z, wih[18], a2);
                // h part: 40 FMAs
#pragma unroll
                for (int q = 0; q < 10; ++q) {
                    float4 f = h4[q];
                    a0 = fmaf(f.x, whh[4*q+0], a0);
                    a1 = fmaf(f.y, whh[4*q+1], a1);
                    a2 = fmaf(f.z, whh[4*q+2], a2);
                    a3 = fmaf(f.w, whh[4*q+3], a3);
                }
                float acc = (a0 + a1) + (a2 + a3);
                float av = gate_act(acc, mulk);     // pre-activated gate
                float bv = __shfl_xor(av, 1);
                float cv = __shfl_xor(av, 2);
                float dv = __shfl_xor(bv, 2);
                // lane 4u+0: av=i, bv=f, cv=g~, dv=o
                if (g == 0) {
                    cc = fmaf(bv, cc, av * cv);
                    hh = dv * tanh_fast(cc);
                    s_h[(t + 1) & 1][u] = hh;
                    s_ring[t][u] = hh;
                }
            }
            __syncthreads();
        }

        // ---- consume chunk: LN + MLP + head (8 threads/step x 5 rows) ----
        {
            const int st = tid & 31;
            const int q8 = tid >> 5;   // 0..7, uniform-ish per half-wave
            float hv[HH];
#pragma unroll
            for (int k = 0; k < HH; ++k) hv[k] = s_ring[st][k];
            float m0 = 0.f, m1 = 0.f, q0 = 0.f, q1 = 0.f;
#pragma unroll
            for (int k = 0; k < HH; k += 2) {
                m0 += hv[k]; m1 += hv[k + 1];
                q0 = fmaf(hv[k], hv[k], q0); q1 = fmaf(hv[k + 1], hv[k + 1], q1);
            }
            float mu = (m0 + m1) * (1.0f / HH);
            float var = (q0 + q1) * (1.0f / HH) - mu * mu;
            float inv = 1.0f / sqrtf(var + 1e-5f);
#pragma unroll
            for (int k = 0; k < HH; ++k)
                hv[k] = fmaf((hv[k] - mu) * inv, s_lng[k], s_lnb[k]);  // hv := ln
            float part = 0.f;
#pragma unroll
            for (int kk = 0; kk < 5; ++kk) {
                int k = q8 * 5 + kk;
                part = fmaf(sigm_fast(hv[k]), s_Wo[k], part);
            }
            __syncthreads();   // all ring reads done -> reuse ring for r1
            float r1v[5];
#pragma unroll
            for (int jj = 0; jj < 5; ++jj) {
                int j = q8 * 5 + jj;
                const float4* wr = (const float4*)&s_W1[j * HH];
                float a0 = s_b1[j], a1 = 0.f;
#pragma unroll
                for (int q = 0; q < 10; ++q) {
                    float4 w4 = wr[q];
                    a0 = fmaf(w4.x, hv[4*q+0], a0); a1 = fmaf(w4.y, hv[4*q+1], a1);
                    a0 = fmaf(w4.z, hv[4*q+2], a0); a1 = fmaf(w4.w, hv[4*q+3], a1);
                }
                r1v[jj] = tanh_fast(a0 + a1);
                s_ring[st][j] = r1v[jj];
            }
            __syncthreads();
            float rr[HH];
#pragma unroll
            for (int k = 0; k < HH; ++k) rr[k] = s_ring[st][k];
#pragma unroll
            for (int jj = 0; jj < 5; ++jj) {
                int j = q8 * 5 + jj;
                const float4* wr = (const float4*)&s_W2[j * HH];
                float a0 = s_b2[j], a1 = 0.f;
#pragma unroll
                for (int q = 0; q < 10; ++q) {
                    float4 w4 = wr[q];
                    a0 = fmaf(w4.x, rr[4*q+0], a0); a1 = fmaf(w4.y, rr[4*q+1], a1);
                    a0 = fmaf(w4.z, rr[4*q+2], a0); a1 = fmaf(w4.w, rr[4*q+3], a1);
                }
                float r2 = tanh_fast(a0 + a1);
                part = fmaf(r2, s_Wo[j], part);
            }
            s_part[tid] = part;
            __syncthreads();
            if (tid < CH) {
                float tot = bo0;
#pragma unroll
                for (int qq = 0; qq < 8; ++qq) tot += s_part[tid + 32 * qq];
                float raw = tanh_fast(tot);
                float sg = (fabsf(raw) >= thrv) ? raw : 0.0f;
                out[(size_t)b * SS + (size_t)ch * CH + tid] = sg;
            }
            // ring rewrites next chunk happen after next stage barrier; s_part
            // reads are ordered by the barrier above -> no extra barrier needed
        }
    }

    // ---- final states + threshold scalar ----
    if (isGate && g == 0) {
        out[(size_t)BB * SS + (size_t)b * HH + u] = hh;
        out[(size_t)BB * SS + (size_t)BB * HH + (size_t)b * HH + u] = cc;
    }
    if (b == 0 && tid == 0) {
        out[(size_t)BB * SS + 2 * (size_t)BB * HH] = thrv;
    }
}

extern "C" void kernel_launch(void* const* d_in, const int* in_sizes, int n_in,
                              void* d_out, int out_size, void* d_ws, size_t ws_size,
                              hipStream_t stream) {
    const float* x    = (const float*)d_in[0];
    const float* W_ih = (const float*)d_in[1];
    const float* W_hh = (const float*)d_in[2];
    const float* b_ih = (const float*)d_in[3];
    const float* b_hh = (const float*)d_in[4];
    const float* ln_g = (const float*)d_in[5];
    const float* ln_b = (const float*)d_in[6];
    const float* W1   = (const float*)d_in[7];
    const float* b1   = (const float*)d_in[8];
    const float* W2   = (const float*)d_in[9];
    const float* b2   = (const float*)d_in[10];
    const float* Wo   = (const float*)d_in[11];
    const float* bo   = (const float*)d_in[12];
    const float* lt   = (const float*)d_in[13];
    float* out = (float*)d_out;

    lstm_fused<<<dim3(BB), dim3(256), 0, stream>>>(
        x, W_ih, W_hh, b_ih, b_hh, ln_g, ln_b, W1, b1, W2, b2, Wo, bo, lt, out);
}

// Round 7
// 1214.651 us; speedup vs baseline: 2.0306x; 1.0133x over previous
//
#include <hip/hip_runtime.h>
#include <math.h>

#define BB 512
#define SS 2048
#define DD 19
#define HH 40
#define CH 32
#define NCH (SS / CH)   // 64 chunks
#define RS 41           // ring row stride ([t][RS]); banks 9t+k, conflict-free
#define HS 48           // h buffer stride (16B aligned)

__device__ __forceinline__ float gate_act(float a, float mulk) {
    // mulk=1: sigmoid(a); mulk=2: tanh(a). 1 - mulk/(exp(mulk*a)+1), NaN-free.
    float e = __expf(a * mulk);
    float r = __builtin_amdgcn_rcpf(e + 1.0f);
    return fmaf(-mulk, r, 1.0f);
}
__device__ __forceinline__ float tanh_fast(float x) {
    float e = __expf(2.0f * x);
    float r = __builtin_amdgcn_rcpf(e + 1.0f);
    return fmaf(-2.0f, r, 1.0f);
}
__device__ __forceinline__ float sigm_fast(float x) {
    float e = __expf(x);
    float r = __builtin_amdgcn_rcpf(e + 1.0f);
    return fmaf(-1.0f, r, 1.0f);
}

__global__ __launch_bounds__(256, 2)  // VGPR cap 256 (no spill), 2 blocks/CU
void lstm_fused(const float* __restrict__ x,
                const float* __restrict__ W_ih,
                const float* __restrict__ W_hh,
                const float* __restrict__ b_ih,
                const float* __restrict__ b_hh,
                const float* __restrict__ ln_g,
                const float* __restrict__ ln_b,
                const float* __restrict__ W1,
                const float* __restrict__ b1,
                const float* __restrict__ W2,
                const float* __restrict__ b2,
                const float* __restrict__ Wo,
                const float* __restrict__ bo,
                const float* __restrict__ log_thr,
                float* __restrict__ out) {
    __shared__ float s_ring[CH][RS];             // h history; reused for r1
    __shared__ __align__(16) float s_h[2][HS];   // double-buffered current h
    __shared__ __align__(16) float s_x[CH][20];  // staged x chunk (19 + 1 pad)
    __shared__ __align__(16) float s_W1[HH * HH];
    __shared__ __align__(16) float s_W2[HH * HH];
    __shared__ float s_lng[HH], s_lnb[HH], s_Wo[HH], s_b1[HH], s_b2[HH];
    __shared__ float s_part[256];

    const int tid = threadIdx.x;
    const int b = blockIdx.x;

    // ---- cooperative staging of post-LSTM weights ----
    for (int i = tid; i < HH * HH; i += 256) { s_W1[i] = W1[i]; s_W2[i] = W2[i]; }
    if (tid < HH) {
        s_lng[tid] = ln_g[tid]; s_lnb[tid] = ln_b[tid]; s_Wo[tid] = Wo[tid];
        s_b1[tid] = b1[tid]; s_b2[tid] = b2[tid];
    }
    if (tid < HS) { s_h[0][tid] = 0.0f; s_h[1][tid] = 0.0f; }

    const float bo0 = bo[0];
    const float thrv = expf(log_thr[0]);

    // ---- gate thread setup: thread 4u+g owns gate row g*40+u ----
    const bool isGate = tid < 4 * HH;   // 160 gate threads (2.5 waves)
    const int g = tid & 3;
    const int u = tid >> 2;             // unit, <40 for gate threads
    const int grow = g * HH + u;
    const float mulk = (g == 2) ? 2.0f : 1.0f;

    float wih[DD];
    float whh[HH];
    float bsum = 0.0f;
    if (isGate) {
#pragma unroll
        for (int d = 0; d < DD; ++d) wih[d] = W_ih[grow * DD + d];
        const float4* wr = (const float4*)&W_hh[grow * HH];
#pragma unroll
        for (int q = 0; q < 10; ++q) {
            float4 f = wr[q];
            whh[4*q] = f.x; whh[4*q+1] = f.y; whh[4*q+2] = f.z; whh[4*q+3] = f.w;
        }
        bsum = b_ih[grow] + b_hh[grow];
    }
    float cc = 0.0f, hh = 0.0f;   // live in g==0 lanes

    // ---- x prefetch registers (3 elements/thread, chunk staged via regs) ----
    const int i0 = tid, i1 = tid + 256, i2 = tid + 512;     // of CH*DD = 608
    const int st0 = i0 / DD, d0 = i0 % DD;
    const int st1 = i1 / DD, d1 = i1 % DD;
    const int st2 = i2 / DD, d2 = i2 % DD;
    float xr0 = 0.f, xr1 = 0.f, xr2 = 0.f;
    {
        const float* xp = x + (size_t)b * SS * DD;   // chunk 0
        xr0 = xp[i0];
        xr1 = xp[i1];
        if (i2 < CH * DD) xr2 = xp[i2];
    }

    __syncthreads();   // weights + h init visible

    for (int ch = 0; ch < NCH; ++ch) {
        // ---- stage x chunk from prefetch regs; issue next chunk's loads ----
        s_x[st0][d0] = xr0;
        s_x[st1][d1] = xr1;
        if (i2 < CH * DD) s_x[st2][d2] = xr2;
        if (ch + 1 < NCH) {
            const float* xp = x + ((size_t)b * SS + (size_t)(ch + 1) * CH) * DD;
            xr0 = xp[i0];
            xr1 = xp[i1];
            if (i2 < CH * DD) xr2 = xp[i2];
        }
        __syncthreads();

        // ---- 32 recurrent steps, ONE barrier each ----
        for (int t = 0; t < CH; ++t) {
            if (isGate) {
                const float4* h4 = (const float4*)s_h[t & 1];
                const float4* x4 = (const float4*)&s_x[t][0];
                float a0 = bsum, a1 = 0.f, a2 = 0.f, a3 = 0.f;
                // x part: 19 FMAs (float4 bcast reads; [19] slot is pad, unused)
                float4 xa = x4[0], xb = x4[1], xc = x4[2], xd = x4[3], xe = x4[4];
                a0 = fmaf(xa.x, wih[0], a0);  a1 = fmaf(xa.y, wih[1], a1);
                a2 = fmaf(xa.z, wih[2], a2);  a3 = fmaf(xa.w, wih[3], a3);
                a0 = fmaf(xb.x, wih[4], a0);  a1 = fmaf(xb.y, wih[5], a1);
                a2 = fmaf(xb.z, wih[6], a2);  a3 = fmaf(xb.w, wih[7], a3);
                a0 = fmaf(xc.x, wih[8], a0);  a1 = fmaf(xc.y, wih[9], a1);
                a2 = fmaf(xc.z, wih[10], a2); a3 = fmaf(xc.w, wih[11], a3);
                a0 = fmaf(xd.x, wih[12], a0); a1 = fmaf(xd.y, wih[13], a1);
                a2 = fmaf(xd.z, wih[14], a2); a3 = fmaf(xd.w, wih[15], a3);
                a0 = fmaf(xe.x, wih[16], a0); a1 = fmaf(xe.y, wih[17], a1);
                a2 = fmaf(xe.z, wih[18], a2);
                // h part: 40 FMAs
#pragma unroll
                for (int q = 0; q < 10; ++q) {
                    float4 f = h4[q];
                    a0 = fmaf(f.x, whh[4*q+0], a0);
                    a1 = fmaf(f.y, whh[4*q+1], a1);
                    a2 = fmaf(f.z, whh[4*q+2], a2);
                    a3 = fmaf(f.w, whh[4*q+3], a3);
                }
                float acc = (a0 + a1) + (a2 + a3);
                float av = gate_act(acc, mulk);     // pre-activated gate
                float bv = __shfl_xor(av, 1);
                float cv = __shfl_xor(av, 2);
                float dv = __shfl_xor(bv, 2);
                // lane 4u+0: av=i, bv=f, cv=g~, dv=o
                if (g == 0) {
                    cc = fmaf(bv, cc, av * cv);
                    hh = dv * tanh_fast(cc);
                    s_h[(t + 1) & 1][u] = hh;
                    s_ring[t][u] = hh;
                }
            }
            __syncthreads();
        }

        // ---- consume chunk: LN + MLP + head (8 threads/step x 5 rows) ----
        {
            const int st = tid & 31;
            const int q8 = tid >> 5;   // 0..7
            float hv[HH];
#pragma unroll
            for (int k = 0; k < HH; ++k) hv[k] = s_ring[st][k];
            float m0 = 0.f, m1 = 0.f, q0 = 0.f, q1 = 0.f;
#pragma unroll
            for (int k = 0; k < HH; k += 2) {
                m0 += hv[k]; m1 += hv[k + 1];
                q0 = fmaf(hv[k], hv[k], q0); q1 = fmaf(hv[k + 1], hv[k + 1], q1);
            }
            float mu = (m0 + m1) * (1.0f / HH);
            float var = (q0 + q1) * (1.0f / HH) - mu * mu;
            float inv = 1.0f / sqrtf(var + 1e-5f);
#pragma unroll
            for (int k = 0; k < HH; ++k)
                hv[k] = fmaf((hv[k] - mu) * inv, s_lng[k], s_lnb[k]);  // hv := ln
            // sigWo: STATIC full loop in every thread (rule #20: no runtime
            // index into a register array). Redundant compute, kept by q8==0.
            float part = 0.f;
#pragma unroll
            for (int k = 0; k < HH; ++k)
                part = fmaf(sigm_fast(hv[k]), s_Wo[k], part);
            if (q8 != 0) part = 0.f;
            __syncthreads();   // all ring reads done -> reuse ring for r1
            float r1v[5];
#pragma unroll
            for (int jj = 0; jj < 5; ++jj) {
                int j = q8 * 5 + jj;
                const float4* wr = (const float4*)&s_W1[j * HH];
                float a0 = s_b1[j], a1 = 0.f;
#pragma unroll
                for (int q = 0; q < 10; ++q) {
                    float4 w4 = wr[q];
                    a0 = fmaf(w4.x, hv[4*q+0], a0); a1 = fmaf(w4.y, hv[4*q+1], a1);
                    a0 = fmaf(w4.z, hv[4*q+2], a0); a1 = fmaf(w4.w, hv[4*q+3], a1);
                }
                r1v[jj] = tanh_fast(a0 + a1);
                s_ring[st][j] = r1v[jj];
            }
            __syncthreads();
            float rr[HH];
#pragma unroll
            for (int k = 0; k < HH; ++k) rr[k] = s_ring[st][k];
#pragma unroll
            for (int jj = 0; jj < 5; ++jj) {
                int j = q8 * 5 + jj;
                const float4* wr = (const float4*)&s_W2[j * HH];
                float a0 = s_b2[j], a1 = 0.f;
#pragma unroll
                for (int q = 0; q < 10; ++q) {
                    float4 w4 = wr[q];
                    a0 = fmaf(w4.x, rr[4*q+0], a0); a1 = fmaf(w4.y, rr[4*q+1], a1);
                    a0 = fmaf(w4.z, rr[4*q+2], a0); a1 = fmaf(w4.w, rr[4*q+3], a1);
                }
                float r2 = tanh_fast(a0 + a1);
                part = fmaf(r2, s_Wo[j], part);
            }
            s_part[tid] = part;
            __syncthreads();
            if (tid < CH) {
                float tot = bo0;
#pragma unroll
                for (int qq = 0; qq < 8; ++qq) tot += s_part[tid + 32 * qq];
                float raw = tanh_fast(tot);
                float sg = (fabsf(raw) >= thrv) ? raw : 0.0f;
                out[(size_t)b * SS + (size_t)ch * CH + tid] = sg;
            }
        }
    }

    // ---- final states + threshold scalar ----
    if (isGate && g == 0) {
        out[(size_t)BB * SS + (size_t)b * HH + u] = hh;
        out[(size_t)BB * SS + (size_t)BB * HH + (size_t)b * HH + u] = cc;
    }
    if (b == 0 && tid == 0) {
        out[(size_t)BB * SS + 2 * (size_t)BB * HH] = thrv;
    }
}

extern "C" void kernel_launch(void* const* d_in, const int* in_sizes, int n_in,
                              void* d_out, int out_size, void* d_ws, size_t ws_size,
                              hipStream_t stream) {
    const float* x    = (const float*)d_in[0];
    const float* W_ih = (const float*)d_in[1];
    const float* W_hh = (const float*)d_in[2];
    const float* b_ih = (const float*)d_in[3];
    const float* b_hh = (const float*)d_in[4];
    const float* ln_g = (const float*)d_in[5];
    const float* ln_b = (const float*)d_in[6];
    const float* W1   = (const float*)d_in[7];
    const float* b1   = (const float*)d_in[8];
    const float* W2   = (const float*)d_in[9];
    const float* b2   = (const float*)d_in[10];
    const float* Wo   = (const float*)d_in[11];
    const float* bo   = (const float*)d_in[12];
    const float* lt   = (const float*)d_in[13];
    float* out = (float*)d_out;

    lstm_fused<<<dim3(BB), dim3(256), 0, stream>>>(
        x, W_ih, W_hh, b_ih, b_hh, ln_g, ln_b, W1, b1, W2, b2, Wo, bo, lt, out);
}